// Round 1
// 131.983 us; speedup vs baseline: 1.0334x; 1.0334x over previous
//
#include <hip/hip_runtime.h>
#include <math.h>
#include <stdint.h>

#define VOCAB 100000
#define DIM   128
#define BATCH 16384
#define CMAX  10
#define KNEG  5

typedef float f32x4 __attribute__((ext_vector_type(4)));

// Numerically stable log(sigmoid(x)) = min(x,0) - log1p(exp(-|x|))
__device__ __forceinline__ float log_sigmoid(float x) {
    return fminf(x, 0.0f) - log1pf(expf(-fabsf(x)));
}

// DPP-based 32-lane sum: after 5 dependent VALU adds, lane 31 holds
// sum(lanes 0..31) and lane 63 holds sum(lanes 32..63).
#define DPP_ADD_STEP(v, ctrl)                                                  \
    v += __int_as_float(__builtin_amdgcn_update_dpp(                           \
        0, __float_as_int(v), (ctrl), 0xF, 0xF, false))

__device__ __forceinline__ float dpp_reduce32_to_lane31(float v) {
    DPP_ADD_STEP(v, 0x111);  // row_shr:1
    DPP_ADD_STEP(v, 0x112);  // row_shr:2
    DPP_ADD_STEP(v, 0x114);  // row_shr:4
    DPP_ADD_STEP(v, 0x118);  // row_shr:8
    DPP_ADD_STEP(v, 0x142);  // row_bcast:15
    return v;
}

// ---------------------------------------------------------------------------
// Fused kernel: ONE WAVE (64 lanes) per sample. Half-wave h owns scores
// j = h*8 .. h*8+7 (j=15 is a dummy slot). 9 row gathers (t + 8 rows) are
// issued back-to-back via inline asm, giving 9-deep MLP per wave (was 5),
// then consumed with STAGED vmcnt(7-jj) waits so each dot+DPP-reduce
// overlaps the remaining load returns. t-row fetched once per sample
// (was 4x). The loss math (log_sigmoid) is fused in, parallelized over
// 16 lanes (8 per half) after a lane31/63 broadcast, so kernel B shrinks
// to a 128 KB float2 reduction.
// ---------------------------------------------------------------------------
__global__ __launch_bounds__(256) void score_loss_kernel(
    const int*   __restrict__ tgt,
    const int*   __restrict__ ctx,
    const int*   __restrict__ lens,
    const int*   __restrict__ neg,
    const float* __restrict__ in_emb,
    const float* __restrict__ out_emb,
    float2*      __restrict__ per_sample,  // ws: [BATCH] (pos_per, neg_per)
    float*       __restrict__ out)
{
    const int tid  = threadIdx.x;
    const int lane = tid & 63;
    const int sub  = lane & 31;              // lane within half-wave
    const int half = lane >> 5;              // which 8-score group
    const int b    = (blockIdx.x * 256 + tid) >> 6;   // one wave per sample

    // zero the accumulators before the reduce kernel's atomics (safe: the
    // reduce kernel only launches after this kernel completes)
    if (blockIdx.x == 0 && tid < 2) out[tid] = 0.0f;

    // ---- index loads (uniform within wave / half-wave) ----
    const int len    = lens[b];
    const int t_word = tgt[b];
    int words[8];
#pragma unroll
    for (int jj = 0; jj < 8; ++jj) {
        const int j = half * 8 + jj;
        if (j < CMAX)             words[jj] = ctx[b * CMAX + j];
        else if (j < CMAX + KNEG) words[jj] = neg[b * KNEG + (j - CMAX)];
        else                      words[jj] = 0;      // dummy slot j=15
    }

    // Drain ALL outstanding vmem (index loads, lens, the out[] store) so the
    // staged vmcnt numbering below counts exactly our 9 asm gathers.
    asm volatile("s_waitcnt vmcnt(0)" ::: "memory");

    // ---- issue all 9 row gathers back-to-back ----
    const uint32_t sub16 = (uint32_t)sub * 16u;
    f32x4 tv;
    {
        uint32_t off = (uint32_t)t_word * (DIM * 4u) + sub16;
        asm volatile("global_load_dwordx4 %0, %1, %2"
                     : "=v"(tv) : "v"(off), "s"(in_emb));
    }
    f32x4 rv[8];
#pragma unroll
    for (int jj = 0; jj < 8; ++jj) {
        uint32_t off = (uint32_t)words[jj] * (DIM * 4u) + sub16;
        asm volatile("global_load_dwordx4 %0, %1, %2"
                     : "=v"(rv[jj]) : "v"(off), "s"(out_emb));
    }

    // ---- staged waits: consume load jj as soon as it (and tv) has landed.
    // vmcnt(7-jj) waits for the (jj+2) oldest of our 9 loads = tv, rv[0..jj].
    float p[8];
#pragma unroll
    for (int jj = 0; jj < 8; ++jj) {
        asm volatile("s_waitcnt vmcnt(%[cnt])"
                     : "+v"(rv[jj]), "+v"(tv)
                     : [cnt] "i"(7 - jj)
                     : "memory");
        float d = tv.x * rv[jj].x + tv.y * rv[jj].y +
                  tv.z * rv[jj].z + tv.w * rv[jj].w;
        p[jj] = dpp_reduce32_to_lane31(d);   // valid on lanes 31 / 63
    }

    // ---- fused loss: broadcast the 8 half-scores to all lanes of the half,
    // then lanes 0..7 (half 0) and 32..39 (half 1) each handle one score.
    float bc[8];
#pragma unroll
    for (int jj = 0; jj < 8; ++jj) bc[jj] = __shfl(p[jj], 31, 32);

    const int sel = sub & 7;
    float a0 = (sel & 1) ? bc[1] : bc[0];
    float a1 = (sel & 1) ? bc[3] : bc[2];
    float a2 = (sel & 1) ? bc[5] : bc[4];
    float a3 = (sel & 1) ? bc[7] : bc[6];
    float b0 = (sel & 2) ? a1 : a0;
    float b1 = (sel & 2) ? a3 : a2;
    float s  = (sel & 4) ? b1 : b0;

    const int  j        = half * 8 + sel;
    const bool neg_slot = (j >= CMAX) && (j < CMAX + KNEG);
    const bool active   = (sub < 8);

    float v    = log_sigmoid(neg_slot ? -s : s);
    // j<len implies j<=9 (len<=CMAX), so pos/neg slots never overlap; j=15 dummy
    // fails both predicates.
    float posc = (active && j < len)    ? v : 0.0f;
    float negc = (active && neg_slot)   ? v : 0.0f;

    // sum the 8 lanes of each active group, then combine the two halves
    posc += __shfl_xor(posc, 1, 64);
    posc += __shfl_xor(posc, 2, 64);
    posc += __shfl_xor(posc, 4, 64);
    posc += __shfl_xor(posc, 32, 64);
    negc += __shfl_xor(negc, 1, 64);
    negc += __shfl_xor(negc, 2, 64);
    negc += __shfl_xor(negc, 4, 64);
    negc += __shfl_xor(negc, 32, 64);

    if (lane == 0) {
        float2 r;
        if (len > 0) {
            r.x = -posc / (float)len;
            r.y = -negc * (1.0f / KNEG);
        } else {
            r.x = 0.0f;
            r.y = 0.0f;
        }
        per_sample[b] = r;
    }
}

// ---------------------------------------------------------------------------
// Kernel B: one thread per sample, reads 128 KB of float2 from L2, no
// transcendentals. 64 blocks -> 128 atomics total.
// ---------------------------------------------------------------------------
__global__ __launch_bounds__(256) void reduce_kernel(
    const float2* __restrict__ per_sample,
    float*        __restrict__ out)
{
    const int tid = threadIdx.x;
    const int b   = blockIdx.x * 256 + tid;   // 64 blocks cover BATCH exactly

    const float2 pr = per_sample[b];
    float pos = pr.x;
    float neg = pr.y;

#pragma unroll
    for (int m = 32; m >= 1; m >>= 1) {
        pos += __shfl_xor(pos, m, 64);
        neg += __shfl_xor(neg, m, 64);
    }
    __shared__ float s_pos[4];
    __shared__ float s_neg[4];
    const int wave = tid >> 6;
    if ((tid & 63) == 0) { s_pos[wave] = pos; s_neg[wave] = neg; }
    __syncthreads();
    if (tid == 0) {
        float ps = s_pos[0] + s_pos[1] + s_pos[2] + s_pos[3];
        float ns = s_neg[0] + s_neg[1] + s_neg[2] + s_neg[3];
        atomicAdd(&out[0], ps * (1.0f / BATCH));
        atomicAdd(&out[1], ns * (1.0f / BATCH));
    }
}

extern "C" void kernel_launch(void* const* d_in, const int* in_sizes, int n_in,
                              void* d_out, int out_size, void* d_ws, size_t ws_size,
                              hipStream_t stream) {
    const int*   tgt     = (const int*)  d_in[0];
    const int*   ctx     = (const int*)  d_in[1];
    const int*   lens    = (const int*)  d_in[2];
    const int*   neg     = (const int*)  d_in[3];
    const float* in_emb  = (const float*)d_in[4];
    const float* out_emb = (const float*)d_in[5];
    float* out          = (float*)d_out;
    float2* per_sample  = (float2*)d_ws;      // BATCH * 8 B = 128 KiB scratch

    // one 64-lane wave per sample; 4 samples per 256-thread block
    score_loss_kernel<<<BATCH / 4, 256, 0, stream>>>(
        tgt, ctx, lens, neg, in_emb, out_emb, per_sample, out);

    reduce_kernel<<<BATCH / 256, 256, 0, stream>>>(per_sample, out);
}